// Round 8
// baseline (281.774 us; speedup 1.0000x reference)
//
#include <hip/hip_runtime.h>
#include <math.h>

typedef _Float16 f16_t;
typedef _Float16 f16x8 __attribute__((ext_vector_type(8)));
typedef _Float16 f16x4 __attribute__((ext_vector_type(4)));
typedef _Float16 f16x2 __attribute__((ext_vector_type(2)));
typedef __fp16 h16x2 __attribute__((ext_vector_type(2)));
typedef float f32x4 __attribute__((ext_vector_type(4)));
typedef float f32x2 __attribute__((ext_vector_type(2)));

#define LDS_BYTES 37376

// fp32 -> fp16 weights into d_ws, FRAGMENT-LINEAR (verified r5-r7): for global
// chunk ck (0..11: W1 ck0..3, W2 ck0..7) and feat-16-group f (0..15), the 1 KB
// block at (ck*16+f)*1024 bytes holds the MFMA A-fragment in exact lane order:
// lane l = q*16+c holds feats f*16+c, k = ck*32 + q*8 .. +7.
__global__ void wconv(const float* __restrict__ W1, const float* __restrict__ W2,
                      f16_t* __restrict__ o) {
  int i = blockIdx.x * 256 + threadIdx.x;  // 0..65535
  if (i < 32768) {
    int n = i >> 7, k = i & 127;
    int ck = k >> 5, q = (k >> 3) & 3, j = k & 7;
    int f = n >> 4, c = n & 15;
    o[ck * 8192 + f * 512 + (q * 16 + c) * 8 + j] = (f16_t)W1[i];
  }
  {
    int n = i >> 8, k = i & 255;
    int ck = k >> 5, q = (k >> 3) & 3, j = k & 7;
    int f = n >> 4, c = n & 15;
    o[32768 + ck * 8192 + f * 512 + (q * 16 + c) * 8 + j] = (f16_t)W2[i];
  }
}

__device__ __forceinline__ f16x2 pk2(float a, float b) {
  union { h16x2 h; f16x2 f; } u;
  u.h = __builtin_amdgcn_cvt_pkrtz(a, b);
  return u.f;
}

__device__ __forceinline__ f32x2 max0(f32x2 v) {
  return __builtin_elementwise_max(v, (f32x2){0.f, 0.f});
}

// lgkm-only barrier: orders LDS data; weight loads (VMEM, same-thread data deps
// only) stay in flight across every barrier.
#define LGKMBAR() do { \
    asm volatile("s_waitcnt lgkmcnt(0)" ::: "memory"); \
    __builtin_amdgcn_s_barrier(); } while (0)

#define MFMA16(a, b, d) d = __builtin_amdgcn_mfma_f32_16x16x32_f16(a, b, d, 0, 0, 0)

// Transposed fused MLP: D[feat][edge] = W @ x^T. Tile = 64 edges, 512 threads,
// 8 waves; each wave = one 32-feat row x ALL 64 edges (acc[2][4] = 32 regs).
// r7 (219us) structure retained exactly: weights direct-to-VGPR (fragment-
// linear), zero barriers in both k-loops, 7 lgkm-only barriers, 2 blocks/CU.
// ROUND-8 CHANGE (single variable): all elementwise phases (gather products,
// LN stats, LN normalize, LN2+dot epilogue) rewritten on float2 halves so the
// default fp-contract emits PACKED fp32 (v_pk_fma_f32 / v_pk_add_f32 /
// v_pk_mul_f32 / v_pk_max_f32, full-rate on gfx950). r7 counters: VALUBusy
// 51.5% = top pipe; LN phases ~400 scalar slots/thread -> ~220 packed.
__global__ __launch_bounds__(512) void fused_mlp(
    const float* __restrict__ h,
    const int* __restrict__ src,
    const int* __restrict__ dst,
    const f16_t* __restrict__ wks,
    const float* __restrict__ b1, const float* __restrict__ g1, const float* __restrict__ be1,
    const float* __restrict__ b2, const float* __restrict__ g2, const float* __restrict__ be2,
    const float* __restrict__ w3, const float* __restrict__ b3,
    float* __restrict__ out, int E, int nrows) {
  extern __shared__ __attribute__((aligned(16))) char smem[];
  f16_t* xbuf = (f16_t*)smem;               // x0 [64][128] (16K); later x1 [64][256] (32K)
  float* ssum = (float*)(smem + 32768);     // [8 wf][64 e]
  float* ssq  = (float*)(smem + 34816);     // [8 wf][64 e]
  float* smean = (float*)(smem + 36864);    // [64]
  float* srstd = (float*)(smem + 37120);    // [64]

  const int t = threadIdx.x;
  const int ebase = blockIdx.x * 64;

  const int lane = t & 63;
  const int wf = t >> 6;     // wave 0..7 = feat-row: feats wf*32 .. wf*32+31
  const int c = lane & 15;
  const int q = lane >> 4;
  const int featBase = wf * 32;

  const f16_t* wp = wks + lane * 8;  // + (ck*16 + wf*2 + m2)*512

  // Weight prologue: chunks 0,1 into the 2-deep register ring.
  f16x8 afb[2][2];
#pragma unroll
  for (int m2 = 0; m2 < 2; ++m2) {
    afb[0][m2] = *(const f16x8*)(wp + (0 * 16 + wf * 2 + m2) * 512);
    afb[1][m2] = *(const f16x8*)(wp + (1 * 16 + wf * 2 + m2) * 512);
  }

  // ---------- gather: x0[m][k] = h[src][k]*h[dst][k], fp16, swizzled stride-128 ----
  // 8 threads per edge, 16 floats each; products as packed f32 muls.
  {
    const int m = t >> 3;   // edge 0..63
    const int j = t & 7;    // 16-float slice
    const int e = ebase + m;
    f16_t* xrow = xbuf + m * 128;
    const int g0 = ((j * 2) ^ m) & 15;
    const int g1i = ((j * 2 + 1) ^ m) & 15;
    if (e < E) {
      int si = src[e], di = dst[e];
      si = ((unsigned)si < (unsigned)nrows) ? si : 0;
      di = ((unsigned)di < (unsigned)nrows) ? di : 0;
      const float* hs = h + (long long)si * 128 + j * 16;
      const float* hd = h + (long long)di * 128 + j * 16;
      const float4 a0 = *(const float4*)(hs);
      const float4 a1 = *(const float4*)(hs + 4);
      const float4 a2 = *(const float4*)(hs + 8);
      const float4 a3 = *(const float4*)(hs + 12);
      const float4 c0 = *(const float4*)(hd);
      const float4 c1 = *(const float4*)(hd + 4);
      const float4 c2 = *(const float4*)(hd + 8);
      const float4 c3 = *(const float4*)(hd + 12);
      const f32x2 p0 = (f32x2){a0.x, a0.y} * (f32x2){c0.x, c0.y};
      const f32x2 p1 = (f32x2){a0.z, a0.w} * (f32x2){c0.z, c0.w};
      const f32x2 p2 = (f32x2){a1.x, a1.y} * (f32x2){c1.x, c1.y};
      const f32x2 p3 = (f32x2){a1.z, a1.w} * (f32x2){c1.z, c1.w};
      const f32x2 p4 = (f32x2){a2.x, a2.y} * (f32x2){c2.x, c2.y};
      const f32x2 p5 = (f32x2){a2.z, a2.w} * (f32x2){c2.z, c2.w};
      const f32x2 p6 = (f32x2){a3.x, a3.y} * (f32x2){c3.x, c3.y};
      const f32x2 p7 = (f32x2){a3.z, a3.w} * (f32x2){c3.z, c3.w};
      union { f16x8 v8; f16x2 v2[4]; } u0, u1;
      u0.v2[0] = pk2(p0.x, p0.y);
      u0.v2[1] = pk2(p1.x, p1.y);
      u0.v2[2] = pk2(p2.x, p2.y);
      u0.v2[3] = pk2(p3.x, p3.y);
      u1.v2[0] = pk2(p4.x, p4.y);
      u1.v2[1] = pk2(p5.x, p5.y);
      u1.v2[2] = pk2(p6.x, p6.y);
      u1.v2[3] = pk2(p7.x, p7.y);
      *(f16x8*)(xrow + g0 * 8) = u0.v8;
      *(f16x8*)(xrow + g1i * 8) = u1.v8;
    } else {
      f16x8 z = {};
      *(f16x8*)(xrow + g0 * 8) = z;
      *(f16x8*)(xrow + g1i * 8) = z;
    }
  }
  LGKMBAR();  // b1: x0 visible (weight loads still in flight)

  // ---------- GEMM1: K=128, chunks 0..3, ZERO barriers ----------
  f32x4 acc[2][4];
#pragma unroll
  for (int m2 = 0; m2 < 2; ++m2)
#pragma unroll
    for (int n = 0; n < 4; ++n) acc[m2][n] = (f32x4){0.f, 0.f, 0.f, 0.f};

#pragma unroll
  for (int j = 0; j < 4; ++j) {
    const int gp = ((j * 4 + q) ^ c) & 15;
    const f16_t* xr = xbuf + c * 128 + gp * 8;
    const f16x8 bf0 = *(const f16x8*)(xr);
    const f16x8 bf1 = *(const f16x8*)(xr + 16 * 128);
    const f16x8 bf2 = *(const f16x8*)(xr + 32 * 128);
    const f16x8 bf3 = *(const f16x8*)(xr + 48 * 128);
    const f16x8 a0 = afb[j & 1][0];
    const f16x8 a1 = afb[j & 1][1];
    // Reload this ring slot with chunk j+2 (j=2 -> ck4, j=3 -> ck5: GEMM2's
    // first chunks ride across the whole LN1 phase).
    afb[j & 1][0] = *(const f16x8*)(wp + ((j + 2) * 16 + wf * 2 + 0) * 512);
    afb[j & 1][1] = *(const f16x8*)(wp + ((j + 2) * 16 + wf * 2 + 1) * 512);
    MFMA16(a0, bf0, acc[0][0]);
    MFMA16(a0, bf1, acc[0][1]);
    MFMA16(a0, bf2, acc[0][2]);
    MFMA16(a0, bf3, acc[0][3]);
    MFMA16(a1, bf0, acc[1][0]);
    MFMA16(a1, bf1, acc[1][1]);
    MFMA16(a1, bf2, acc[1][2]);
    MFMA16(a1, bf3, acc[1][3]);
  }

  // ---------- LN1 stats (packed f32) ----------
  {
    f32x2 s2[4], q2[4];
#pragma unroll
    for (int n = 0; n < 4; ++n) { s2[n] = (f32x2){0.f, 0.f}; q2[n] = (f32x2){0.f, 0.f}; }
#pragma unroll
    for (int m2 = 0; m2 < 2; ++m2) {
      const float4 bv = *(const float4*)(b1 + featBase + m2 * 16 + q * 4);
      const f32x2 blo = {bv.x, bv.y}, bhi = {bv.z, bv.w};
#pragma unroll
      for (int n = 0; n < 4; ++n) {
        const f32x2 vlo = acc[m2][n].lo + blo;
        const f32x2 vhi = acc[m2][n].hi + bhi;
        acc[m2][n].lo = vlo; acc[m2][n].hi = vhi;
        s2[n] += vlo; s2[n] += vhi;
        q2[n] += vlo * vlo; q2[n] += vhi * vhi;
      }
    }
#pragma unroll
    for (int n = 0; n < 4; ++n) {
      float s = s2[n].x + s2[n].y, sq = q2[n].x + q2[n].y;
      s += __shfl_xor(s, 16, 64); s += __shfl_xor(s, 32, 64);
      sq += __shfl_xor(sq, 16, 64); sq += __shfl_xor(sq, 32, 64);
      if (q == 0) {
        ssum[wf * 64 + n * 16 + c] = s;
        ssq[wf * 64 + n * 16 + c] = sq;
      }
    }
  }
  LGKMBAR();  // b2: partials visible; all x0 reads drained

  if (t < 64) {
    float s = 0.f, sq = 0.f;
#pragma unroll
    for (int w = 0; w < 8; ++w) { s += ssum[w * 64 + t]; sq += ssq[w * 64 + t]; }
    float mu = s * (1.f / 256.f);
    float var = sq * (1.f / 256.f) - mu * mu;
    smean[t] = mu;
    srstd[t] = rsqrtf(var + 1e-5f);
  }
  LGKMBAR();  // b3: mean/rstd ready

  // ---------- LN1 normalize + ReLU -> x1 [64][256] (packed f32) ----------
  {
    float rs[4], nmr[4];
#pragma unroll
    for (int n = 0; n < 4; ++n) {
      rs[n] = srstd[n * 16 + c];
      nmr[n] = -smean[n * 16 + c] * rs[n];
    }
    const int j0 = (q & 1) * 4;
#pragma unroll
    for (int m2 = 0; m2 < 2; ++m2) {
      const float4 gv = *(const float4*)(g1 + featBase + m2 * 16 + q * 4);
      const float4 bev = *(const float4*)(be1 + featBase + m2 * 16 + q * 4);
      const f32x2 glo = {gv.x, gv.y}, ghi = {gv.z, gv.w};
      const f32x2 belo = {bev.x, bev.y}, behi = {bev.z, bev.w};
      const int g8 = wf * 4 + m2 * 2 + (q >> 1);   // feat 8-f16-group 0..31
      const int gpw = (g8 & 16) | ((g8 ^ c) & 15);
#pragma unroll
      for (int n = 0; n < 4; ++n) {
        const f32x2 rsv = {rs[n], rs[n]}, nmrv = {nmr[n], nmr[n]};
        f32x2 tlo = acc[m2][n].lo * rsv + nmrv;
        tlo = max0(tlo * glo + belo);
        f32x2 thi = acc[m2][n].hi * rsv + nmrv;
        thi = max0(thi * ghi + behi);
        union { f16x4 v4; f16x2 v2[2]; } hh;
        hh.v2[0] = pk2(tlo.x, tlo.y); hh.v2[1] = pk2(thi.x, thi.y);
        *(f16x4*)(xbuf + (n * 16 + c) * 256 + gpw * 8 + j0) = hh.v4;
      }
    }
  }
  LGKMBAR();  // b4: x1 visible

  // ---------- GEMM2: K=256, chunks 4..11, ZERO barriers ----------
  f32x4 acc2[2][4];
#pragma unroll
  for (int m2 = 0; m2 < 2; ++m2)
#pragma unroll
    for (int n = 0; n < 4; ++n) acc2[m2][n] = (f32x4){0.f, 0.f, 0.f, 0.f};

#pragma unroll
  for (int j = 0; j < 8; ++j) {   // global chunk 4+j
    const int g = j * 4 + q;      // 0..31
    const int gp = (g & 16) | ((g ^ c) & 15);
    const f16_t* xr = xbuf + c * 256 + gp * 8;
    const f16x8 bf0 = *(const f16x8*)(xr);
    const f16x8 bf1 = *(const f16x8*)(xr + 16 * 256);
    const f16x8 bf2 = *(const f16x8*)(xr + 32 * 256);
    const f16x8 bf3 = *(const f16x8*)(xr + 48 * 256);
    const f16x8 a0 = afb[j & 1][0];
    const f16x8 a1 = afb[j & 1][1];
    if (j < 6) {  // reload ring slot with chunk 6+j
      afb[j & 1][0] = *(const f16x8*)(wp + ((6 + j) * 16 + wf * 2 + 0) * 512);
      afb[j & 1][1] = *(const f16x8*)(wp + ((6 + j) * 16 + wf * 2 + 1) * 512);
    }
    MFMA16(a0, bf0, acc2[0][0]);
    MFMA16(a0, bf1, acc2[0][1]);
    MFMA16(a0, bf2, acc2[0][2]);
    MFMA16(a0, bf3, acc2[0][3]);
    MFMA16(a1, bf0, acc2[1][0]);
    MFMA16(a1, bf1, acc2[1][1]);
    MFMA16(a1, bf2, acc2[1][2]);
    MFMA16(a1, bf3, acc2[1][3]);
  }

  // ---------- LN2 stats (packed f32) ----------
  {
    f32x2 s2[4], q2[4];
#pragma unroll
    for (int n = 0; n < 4; ++n) { s2[n] = (f32x2){0.f, 0.f}; q2[n] = (f32x2){0.f, 0.f}; }
#pragma unroll
    for (int m2 = 0; m2 < 2; ++m2) {
      const float4 bv = *(const float4*)(b2 + featBase + m2 * 16 + q * 4);
      const f32x2 blo = {bv.x, bv.y}, bhi = {bv.z, bv.w};
#pragma unroll
      for (int n = 0; n < 4; ++n) {
        const f32x2 vlo = acc2[m2][n].lo + blo;
        const f32x2 vhi = acc2[m2][n].hi + bhi;
        acc2[m2][n].lo = vlo; acc2[m2][n].hi = vhi;
        s2[n] += vlo; s2[n] += vhi;
        q2[n] += vlo * vlo; q2[n] += vhi * vhi;
      }
    }
#pragma unroll
    for (int n = 0; n < 4; ++n) {
      float s = s2[n].x + s2[n].y, sq = q2[n].x + q2[n].y;
      s += __shfl_xor(s, 16, 64); s += __shfl_xor(s, 32, 64);
      sq += __shfl_xor(sq, 16, 64); sq += __shfl_xor(sq, 32, 64);
      if (q == 0) {
        ssum[wf * 64 + n * 16 + c] = s;
        ssq[wf * 64 + n * 16 + c] = sq;
      }
    }
  }
  LGKMBAR();  // b5

  if (t < 64) {
    float s = 0.f, sq = 0.f;
#pragma unroll
    for (int w = 0; w < 8; ++w) { s += ssum[w * 64 + t]; sq += ssq[w * 64 + t]; }
    float mu = s * (1.f / 256.f);
    float var = sq * (1.f / 256.f) - mu * mu;
    smean[t] = mu;
    srstd[t] = rsqrtf(var + 1e-5f);
  }
  LGKMBAR();  // b6

  // ---------- LN2 normalize + ReLU + dot(W3) + sigmoid (packed f32) ----------
  {
    float rs[4], nmr[4];
    f32x2 p2[4];
#pragma unroll
    for (int n = 0; n < 4; ++n) {
      rs[n] = srstd[n * 16 + c];
      nmr[n] = -smean[n * 16 + c] * rs[n];
      p2[n] = (f32x2){0.f, 0.f};
    }
#pragma unroll
    for (int m2 = 0; m2 < 2; ++m2) {
      const float4 gv = *(const float4*)(g2 + featBase + m2 * 16 + q * 4);
      const float4 bev = *(const float4*)(be2 + featBase + m2 * 16 + q * 4);
      const float4 wv = *(const float4*)(w3 + featBase + m2 * 16 + q * 4);
      const f32x2 glo = {gv.x, gv.y}, ghi = {gv.z, gv.w};
      const f32x2 belo = {bev.x, bev.y}, behi = {bev.z, bev.w};
      const f32x2 wlo = {wv.x, wv.y}, whi = {wv.z, wv.w};
#pragma unroll
      for (int n = 0; n < 4; ++n) {
        const f32x2 rsv = {rs[n], rs[n]}, nmrv = {nmr[n], nmr[n]};
        f32x2 vlo = acc2[m2][n].lo * rsv + nmrv;
        vlo = max0(vlo * glo + belo);
        p2[n] += vlo * wlo;
        f32x2 vhi = acc2[m2][n].hi * rsv + nmrv;
        vhi = max0(vhi * ghi + behi);
        p2[n] += vhi * whi;
      }
    }
#pragma unroll
    for (int n = 0; n < 4; ++n) {
      float p = p2[n].x + p2[n].y;
      p += __shfl_xor(p, 16, 64); p += __shfl_xor(p, 32, 64);
      if (q == 0) ssum[wf * 64 + n * 16 + c] = p;   // ssum dead after b6 reduce
    }
  }
  LGKMBAR();  // b7
  if (t < 64) {
    int e = ebase + t;
    if (e < E) {
      float sres = b3[0];
#pragma unroll
      for (int w = 0; w < 8; ++w) sres += ssum[w * 64 + t];
      out[e] = 1.f / (1.f + __expf(-sres));
    }
  }
}

extern "C" void kernel_launch(void* const* d_in, const int* in_sizes, int n_in,
                              void* d_out, int out_size, void* d_ws, size_t ws_size,
                              hipStream_t stream) {
  const float* h = (const float*)d_in[0];
  const int* src = (const int*)d_in[1];
  const int* dst = (const int*)d_in[2];
  const float* W1 = (const float*)d_in[3];
  const float* b1 = (const float*)d_in[4];
  const float* g1 = (const float*)d_in[5];
  const float* be1 = (const float*)d_in[6];
  const float* W2 = (const float*)d_in[7];
  const float* b2 = (const float*)d_in[8];
  const float* g2 = (const float*)d_in[9];
  const float* be2 = (const float*)d_in[10];
  const float* W3 = (const float*)d_in[11];
  const float* b3 = (const float*)d_in[12];
  float* out = (float*)d_out;
  const int E = in_sizes[1];
  const int nrows = in_sizes[0] / 128;
  f16_t* wks = (f16_t*)d_ws;  // 98304 f16 = 196608 bytes

  wconv<<<256, 256, 0, stream>>>(W1, W2, wks);
  (void)hipFuncSetAttribute((const void*)fused_mlp,
                            hipFuncAttributeMaxDynamicSharedMemorySize, LDS_BYTES);
  const int tiles = (E + 63) / 64;
  fused_mlp<<<tiles, 512, LDS_BYTES, stream>>>(h, src, dst, wks, b1, g1, be1,
                                               b2, g2, be2, W3, b3, out, E, nrows);
}